// Round 1
// baseline (1362.338 us; speedup 1.0000x reference)
//
#include <hip/hip_runtime.h>
#include <math.h>

#define BB 4
#define UU 512
#define DD 80
#define HH 8
#define FFND 2048
#define LL 12
#define SEGC 32
#define LCC 50
#define RCC 8
#define NSEG 16
#define RCL 128
#define KK 640
#define ROWS (BB*KK)        // 2560
#define OUTD 768
#define NSPLIT 4
#define EPSF 1e-5f
#define SCALEF 0.31622776601683794f  // (D/H)^-0.5 = 10^-0.5

// ---------------- gather: x0 = concat(rc, utt) ----------------
__global__ __launch_bounds__(256) void k_gather(const float* __restrict__ mel,
                                                float* __restrict__ x) {
  int idx = blockIdx.x * 256 + threadIdx.x;
  if (idx >= ROWS * DD) return;
  int d = idx % DD;
  int row = idx / DD;
  int b = row / KK;
  int j = row % KK;
  int pos;
  if (j < RCL) {
    int i = j >> 3, r = j & 7;
    pos = (i < NSEG - 1) ? (i + 1) * SEGC + r : UU + r;
  } else {
    pos = j - RCL;
  }
  x[idx] = mel[(b * (UU + RCC) + pos) * DD + d];
}

// ---------------- A: LN_in fused + QKV GEMM ----------------
// grid (ROWS/32, 3), block 256. col-tile ct: 0->q, 1->k, 2->v (80 cols each)
__global__ __launch_bounds__(256) void k_qkv(
    const float* __restrict__ x, float* __restrict__ qkv,
    const float* __restrict__ Wq, const float* __restrict__ bq,
    const float* __restrict__ Wkv, const float* __restrict__ bkv,
    const float* __restrict__ lg, const float* __restrict__ lb) {
  __shared__ float s_x[32 * 84];
  __shared__ float s_w[80 * 84];
  __shared__ float s_mu[32], s_ri[32];
  int tid = threadIdx.x;
  int r0 = blockIdx.x * 32;
  int ct = blockIdx.y;
  for (int k = 0; k < 3; ++k) {
    int idx = tid + k * 256;
    if (idx < 640) {
      int row = idx / 20, c4 = idx % 20;
      *reinterpret_cast<float4*>(&s_x[row * 84 + c4 * 4]) =
          *reinterpret_cast<const float4*>(&x[(r0 + row) * DD + c4 * 4]);
    }
  }
  const float* Wbase = (ct == 0) ? Wq : (ct == 1 ? Wkv : (Wkv + 80 * DD));
  for (int k = 0; k < 7; ++k) {
    int idx = tid + k * 256;
    if (idx < 1600) {
      int c = idx / 20, d4 = idx % 20;
      *reinterpret_cast<float4*>(&s_w[c * 84 + d4 * 4]) =
          *reinterpret_cast<const float4*>(&Wbase[c * DD + d4 * 4]);
    }
  }
  __syncthreads();
  // LN stats: 8 threads/row
  {
    int rr = tid >> 3, t8 = tid & 7;
    float sm = 0.f, sq = 0.f;
    for (int d = t8 * 10; d < t8 * 10 + 10; ++d) {
      float v = s_x[rr * 84 + d];
      sm += v; sq += v * v;
    }
    for (int m = 4; m >= 1; m >>= 1) {
      sm += __shfl_xor(sm, m, 8);
      sq += __shfl_xor(sq, m, 8);
    }
    if (t8 == 0) {
      float mu = sm * (1.f / DD);
      float var = sq * (1.f / DD) - mu * mu;
      s_mu[rr] = mu;
      s_ri[rr] = rsqrtf(var + EPSF);
    }
  }
  __syncthreads();
  for (int k = 0; k < 10; ++k) {
    int e = tid + k * 256;  // < 2560
    int row = e / 80, d = e % 80;
    s_x[row * 84 + d] = (s_x[row * 84 + d] - s_mu[row]) * s_ri[row] * lg[d] + lb[d];
  }
  __syncthreads();
  int ty = tid >> 4, tx = tid & 15;
  float acc[2][5] = {};
  for (int d4 = 0; d4 < 20; ++d4) {
    float4 a0 = *reinterpret_cast<const float4*>(&s_x[(2 * ty) * 84 + d4 * 4]);
    float4 a1 = *reinterpret_cast<const float4*>(&s_x[(2 * ty + 1) * 84 + d4 * 4]);
#pragma unroll
    for (int j = 0; j < 5; ++j) {
      float4 w = *reinterpret_cast<const float4*>(&s_w[(tx + 16 * j) * 84 + d4 * 4]);
      acc[0][j] += a0.x * w.x + a0.y * w.y + a0.z * w.z + a0.w * w.w;
      acc[1][j] += a1.x * w.x + a1.y * w.y + a1.z * w.z + a1.w * w.w;
    }
  }
  const float* bias = (ct == 0) ? bq : (bkv + (ct == 2 ? 80 : 0));
  for (int i2 = 0; i2 < 2; ++i2)
    for (int j = 0; j < 5; ++j) {
      int c = tx + 16 * j;
      int grow = r0 + 2 * ty + i2;
      qkv[grow * 240 + ct * 80 + c] = acc[i2][j] + bias[c];
    }
}

// ---------------- B: masked segmented attention ----------------
// grid (NSEG, H, B), block 64
__global__ __launch_bounds__(64) void k_attn(const float* __restrict__ qkv,
                                             float* __restrict__ attn,
                                             const int* __restrict__ lengths) {
  int i = blockIdx.x, h = blockIdx.y, b = blockIdx.z;
  int tid = threadIdx.x;
  int s = i * SEGC - LCC; if (s < 0) s = 0;
  int e = (i + 1) * SEGC;
  int nk = RCC + (e - s);  // <= 90
  __shared__ float s_k[90 * 10], s_v[90 * 10], s_q[40 * 10];
  __shared__ float s_p[40 * 90], s_kb[90], s_den[40];
  int len = lengths[b];
  for (int j = tid; j < nk; j += 64) {
    int kr = (j < RCC) ? i * RCC + j : RCL + s + (j - RCC);
    const float* kp = &qkv[(b * KK + kr) * 240 + 80 + h * 10];
    const float* vp = &qkv[(b * KK + kr) * 240 + 160 + h * 10];
    for (int d = 0; d < 10; ++d) { s_k[j * 10 + d] = kp[d]; s_v[j * 10 + d] = vp[d]; }
    s_kb[j] = (kr >= len + RCL) ? -1e8f : 0.f;
  }
  if (tid < 40) {
    int j = tid;
    int qr = (j < RCC) ? i * RCC + j : RCL + i * SEGC + (j - RCC);
    const float* qp = &qkv[(b * KK + qr) * 240 + h * 10];
    for (int d = 0; d < 10; ++d) s_q[j * 10 + d] = qp[d];
  }
  __syncthreads();
  for (int p = tid; p < 3600; p += 64) {
    int q = p / 90, jk = p % 90;
    float sc = -1e30f;
    if (jk < nk) {
      float dot = 0.f;
#pragma unroll
      for (int d = 0; d < 10; ++d) dot += s_q[q * 10 + d] * s_k[jk * 10 + d];
      sc = dot * SCALEF + s_kb[jk];
    }
    s_p[p] = sc;
  }
  __syncthreads();
  if (tid < 40) {
    float m = -1e30f;
    for (int kx = 0; kx < 90; ++kx) m = fmaxf(m, s_p[tid * 90 + kx]);
    float sum = 0.f;
    for (int kx = 0; kx < 90; ++kx) {
      float ev = __expf(s_p[tid * 90 + kx] - m);
      s_p[tid * 90 + kx] = ev;
      sum += ev;
    }
    s_den[tid] = sum;
  }
  __syncthreads();
  for (int po = tid; po < 400; po += 64) {
    int q = po / 10, d = po % 10;
    float o = 0.f;
    for (int kx = 0; kx < 90; ++kx) o += s_p[q * 90 + kx] * s_v[kx * 10 + d];
    int qr = (q < RCC) ? i * RCC + q : RCL + i * SEGC + (q - RCC);
    attn[(b * KK + qr) * DD + h * 10 + d] = o / s_den[q];
  }
}

// ---------------- C: out-proj + bias + residual + LN_ff ----------------
// grid ROWS/16, block 256
__global__ __launch_bounds__(256) void k_oproj(
    const float* __restrict__ attn, const float* __restrict__ Wo,
    const float* __restrict__ bo, const float* __restrict__ x,
    float* __restrict__ res, float* __restrict__ ffln,
    const float* __restrict__ fg, const float* __restrict__ fb) {
  __shared__ float s_at[16 * 84], s_x2[16 * 84], s_wo[80 * 84];
  int tid = threadIdx.x;
  int r0 = blockIdx.x * 16;
  for (int k = 0; k < 2; ++k) {
    int idx = tid + k * 256;
    if (idx < 320) {
      int row = idx / 20, c4 = idx % 20;
      *reinterpret_cast<float4*>(&s_at[row * 84 + c4 * 4]) =
          *reinterpret_cast<const float4*>(&attn[(r0 + row) * DD + c4 * 4]);
      *reinterpret_cast<float4*>(&s_x2[row * 84 + c4 * 4]) =
          *reinterpret_cast<const float4*>(&x[(r0 + row) * DD + c4 * 4]);
    }
  }
  for (int k = 0; k < 7; ++k) {
    int idx = tid + k * 256;
    if (idx < 1600) {
      int c = idx / 20, d4 = idx % 20;
      *reinterpret_cast<float4*>(&s_wo[c * 84 + d4 * 4]) =
          *reinterpret_cast<const float4*>(&Wo[c * DD + d4 * 4]);
    }
  }
  __syncthreads();
  int r = tid >> 4, tx = tid & 15;
  float acc[5] = {};
  for (int d4 = 0; d4 < 20; ++d4) {
    float4 a = *reinterpret_cast<const float4*>(&s_at[r * 84 + d4 * 4]);
#pragma unroll
    for (int j = 0; j < 5; ++j) {
      float4 w = *reinterpret_cast<const float4*>(&s_wo[(tx + 16 * j) * 84 + d4 * 4]);
      acc[j] += a.x * w.x + a.y * w.y + a.z * w.z + a.w * w.w;
    }
  }
  float val[5];
  float sm = 0.f, sq = 0.f;
#pragma unroll
  for (int j = 0; j < 5; ++j) {
    int c = tx + 16 * j;
    float v = acc[j] + bo[c] + s_x2[r * 84 + c];
    val[j] = v;
    res[(r0 + r) * DD + c] = v;
    sm += v; sq += v * v;
  }
  for (int m = 8; m >= 1; m >>= 1) {
    sm += __shfl_xor(sm, m, 16);
    sq += __shfl_xor(sq, m, 16);
  }
  float mu = sm * (1.f / DD);
  float ri = rsqrtf(sq * (1.f / DD) - mu * mu + EPSF);
#pragma unroll
  for (int j = 0; j < 5; ++j) {
    int c = tx + 16 * j;
    ffln[(r0 + r) * DD + c] = (val[j] - mu) * ri * fg[c] + fb[c];
  }
}

// ---------------- D: FFN1 + relu : h = relu(ffln @ W1^T + b1) ----------------
// grid (ROWS/64, FFND/64), block 256
__global__ __launch_bounds__(256) void k_ffn1(
    const float* __restrict__ ffln, const float* __restrict__ W1,
    const float* __restrict__ b1, float* __restrict__ h) {
  __shared__ float s_a[64 * 84], s_w[64 * 84];
  int tid = threadIdx.x;
  int r0 = blockIdx.x * 64, c0 = blockIdx.y * 64;
  for (int k = 0; k < 5; ++k) {
    int idx = tid + k * 256;  // exactly 1280
    int row = idx / 20, c4 = idx % 20;
    *reinterpret_cast<float4*>(&s_a[row * 84 + c4 * 4]) =
        *reinterpret_cast<const float4*>(&ffln[(r0 + row) * DD + c4 * 4]);
    *reinterpret_cast<float4*>(&s_w[row * 84 + c4 * 4]) =
        *reinterpret_cast<const float4*>(&W1[(c0 + row) * DD + c4 * 4]);
  }
  __syncthreads();
  int ty = tid >> 4, tx = tid & 15;
  float acc[4][4] = {};
  for (int d4 = 0; d4 < 20; ++d4) {
    float4 a[4], w[4];
#pragma unroll
    for (int i2 = 0; i2 < 4; ++i2)
      a[i2] = *reinterpret_cast<const float4*>(&s_a[(4 * ty + i2) * 84 + d4 * 4]);
#pragma unroll
    for (int j = 0; j < 4; ++j)
      w[j] = *reinterpret_cast<const float4*>(&s_w[(tx + 16 * j) * 84 + d4 * 4]);
#pragma unroll
    for (int i2 = 0; i2 < 4; ++i2)
#pragma unroll
      for (int j = 0; j < 4; ++j)
        acc[i2][j] += a[i2].x * w[j].x + a[i2].y * w[j].y +
                      a[i2].z * w[j].z + a[i2].w * w[j].w;
  }
  for (int i2 = 0; i2 < 4; ++i2)
    for (int j = 0; j < 4; ++j) {
      int c = c0 + tx + 16 * j;
      float v = acc[i2][j] + b1[c];
      h[(r0 + 4 * ty + i2) * FFND + c] = fmaxf(v, 0.f);
    }
}

// ---------------- E: FFN2 partial GEMM over depth split ----------------
// grid (ROWS/32, NSPLIT), block 256
__global__ __launch_bounds__(256) void k_ffn2(
    const float* __restrict__ h, const float* __restrict__ W2,
    float* __restrict__ part) {
  __shared__ float s_h[32 * 68], s_w2[80 * 68];
  int tid = threadIdx.x;
  int r0 = blockIdx.x * 32;
  int split = blockIdx.y;
  int ty = tid >> 4, tx = tid & 15;
  float acc[2][5] = {};
  for (int sub = 0; sub < 8; ++sub) {
    int dbase = split * 512 + sub * 64;
    __syncthreads();
    for (int k = 0; k < 2; ++k) {
      int idx = tid + k * 256;  // 512
      int row = idx / 16, d4 = idx % 16;
      *reinterpret_cast<float4*>(&s_h[row * 68 + d4 * 4]) =
          *reinterpret_cast<const float4*>(&h[(r0 + row) * FFND + dbase + d4 * 4]);
    }
    for (int k = 0; k < 5; ++k) {
      int idx = tid + k * 256;  // 1280
      int c = idx / 16, d4 = idx % 16;
      *reinterpret_cast<float4*>(&s_w2[c * 68 + d4 * 4]) =
          *reinterpret_cast<const float4*>(&W2[c * FFND + dbase + d4 * 4]);
    }
    __syncthreads();
    for (int d4 = 0; d4 < 16; ++d4) {
      float4 a0 = *reinterpret_cast<const float4*>(&s_h[(2 * ty) * 68 + d4 * 4]);
      float4 a1 = *reinterpret_cast<const float4*>(&s_h[(2 * ty + 1) * 68 + d4 * 4]);
#pragma unroll
      for (int j = 0; j < 5; ++j) {
        float4 w = *reinterpret_cast<const float4*>(&s_w2[(tx + 16 * j) * 68 + d4 * 4]);
        acc[0][j] += a0.x * w.x + a0.y * w.y + a0.z * w.z + a0.w * w.w;
        acc[1][j] += a1.x * w.x + a1.y * w.y + a1.z * w.z + a1.w * w.w;
      }
    }
  }
  for (int i2 = 0; i2 < 2; ++i2)
    for (int j = 0; j < 5; ++j)
      part[split * (ROWS * DD) + (r0 + 2 * ty + i2) * DD + tx + 16 * j] = acc[i2][j];
}

// ---------------- F: combine splits + b2 + residual + LN_out -> x ----------------
// grid ROWS, block 128
__global__ __launch_bounds__(128) void k_comb(
    const float* __restrict__ part, const float* __restrict__ b2,
    const float* __restrict__ res, float* __restrict__ x,
    const float* __restrict__ og, const float* __restrict__ ob) {
  int row = blockIdx.x;
  int t = threadIdx.x;
  __shared__ float rsum[128], rsq[128];
  float v = 0.f;
  if (t < DD) {
    v = part[row * DD + t] + part[ROWS * DD + row * DD + t] +
        part[2 * ROWS * DD + row * DD + t] + part[3 * ROWS * DD + row * DD + t] +
        b2[t] + res[row * DD + t];
  }
  rsum[t] = (t < DD) ? v : 0.f;
  rsq[t] = (t < DD) ? v * v : 0.f;
  __syncthreads();
  for (int m2 = 64; m2 >= 1; m2 >>= 1) {
    if (t < m2) { rsum[t] += rsum[t + m2]; rsq[t] += rsq[t + m2]; }
    __syncthreads();
  }
  float mu = rsum[0] * (1.f / DD);
  float ri = rsqrtf(rsq[0] * (1.f / DD) - mu * mu + EPSF);
  if (t < DD) x[row * DD + t] = (v - mu) * ri * og[t] + ob[t];
}

// ---------------- P: final projection + lengths tail ----------------
// grid (2048/64, OUTD/64), block 256
__global__ __launch_bounds__(256) void k_proj(
    const float* __restrict__ x, const float* __restrict__ Wp,
    const float* __restrict__ bp, const int* __restrict__ lengths,
    float* __restrict__ out) {
  __shared__ float s_a[64 * 84], s_w[64 * 84];
  int tid = threadIdx.x;
  int gr0 = blockIdx.x * 64;
  int c0 = blockIdx.y * 64;
  int b = gr0 / UU;
  int u0 = gr0 % UU;
  for (int k = 0; k < 5; ++k) {
    int idx = tid + k * 256;  // 1280
    int row = idx / 20, c4 = idx % 20;
    *reinterpret_cast<float4*>(&s_a[row * 84 + c4 * 4]) =
        *reinterpret_cast<const float4*>(&x[(b * KK + RCL + u0 + row) * DD + c4 * 4]);
    *reinterpret_cast<float4*>(&s_w[row * 84 + c4 * 4]) =
        *reinterpret_cast<const float4*>(&Wp[(c0 + row) * DD + c4 * 4]);
  }
  __syncthreads();
  int ty = tid >> 4, tx = tid & 15;
  float acc[4][4] = {};
  for (int d4 = 0; d4 < 20; ++d4) {
    float4 a[4], w[4];
#pragma unroll
    for (int i2 = 0; i2 < 4; ++i2)
      a[i2] = *reinterpret_cast<const float4*>(&s_a[(4 * ty + i2) * 84 + d4 * 4]);
#pragma unroll
    for (int j = 0; j < 4; ++j)
      w[j] = *reinterpret_cast<const float4*>(&s_w[(tx + 16 * j) * 84 + d4 * 4]);
#pragma unroll
    for (int i2 = 0; i2 < 4; ++i2)
#pragma unroll
      for (int j = 0; j < 4; ++j)
        acc[i2][j] += a[i2].x * w[j].x + a[i2].y * w[j].y +
                      a[i2].z * w[j].z + a[i2].w * w[j].w;
  }
  for (int i2 = 0; i2 < 4; ++i2)
    for (int j = 0; j < 4; ++j) {
      int c = c0 + tx + 16 * j;
      out[(gr0 + 4 * ty + i2) * OUTD + c] = acc[i2][j] + bp[c];
    }
  if (blockIdx.x == 0 && blockIdx.y == 0 && tid < BB)
    out[BB * UU * OUTD + tid] = (float)lengths[tid];
}

extern "C" void kernel_launch(void* const* d_in, const int* in_sizes, int n_in,
                              void* d_out, int out_size, void* d_ws, size_t ws_size,
                              hipStream_t stream) {
  const float* mel   = (const float*)d_in[0];
  const float* lng   = (const float*)d_in[1];
  const float* lnb   = (const float*)d_in[2];
  const float* Wq    = (const float*)d_in[3];
  const float* bq    = (const float*)d_in[4];
  const float* Wkv   = (const float*)d_in[5];
  const float* bkv   = (const float*)d_in[6];
  const float* Wo    = (const float*)d_in[7];
  const float* bo    = (const float*)d_in[8];
  const float* ffg   = (const float*)d_in[9];
  const float* ffb   = (const float*)d_in[10];
  const float* W1    = (const float*)d_in[11];
  const float* b1    = (const float*)d_in[12];
  const float* W2    = (const float*)d_in[13];
  const float* b2    = (const float*)d_in[14];
  const float* og    = (const float*)d_in[15];
  const float* ob    = (const float*)d_in[16];
  const float* Wp    = (const float*)d_in[17];
  const float* bp    = (const float*)d_in[18];
  const int*   lens  = (const int*)d_in[19];
  float* out = (float*)d_out;

  float* ws   = (float*)d_ws;
  float* x    = ws;                    // ROWS*DD
  float* qkv  = x + ROWS * DD;         // ROWS*240
  float* attn = qkv + ROWS * 240;      // ROWS*DD
  float* res  = attn + ROWS * DD;      // ROWS*DD
  float* ffln = res + ROWS * DD;       // ROWS*DD
  float* h    = ffln + ROWS * DD;      // ROWS*FFND
  float* part = h + ROWS * FFND;       // NSPLIT*ROWS*DD

  k_gather<<<(ROWS * DD + 255) / 256, 256, 0, stream>>>(mel, x);

  for (int l = 0; l < LL; ++l) {
    const float* lWq  = Wq  + l * DD * DD;
    const float* lbq  = bq  + l * DD;
    const float* lWkv = Wkv + l * 2 * DD * DD;
    const float* lbkv = bkv + l * 2 * DD;
    const float* lWo  = Wo  + l * DD * DD;
    const float* lbo  = bo  + l * DD;
    const float* lW1  = W1  + l * FFND * DD;
    const float* lb1  = b1  + l * FFND;
    const float* lW2  = W2  + l * DD * FFND;
    const float* lb2  = b2  + l * DD;

    k_qkv<<<dim3(ROWS / 32, 3), 256, 0, stream>>>(
        x, qkv, lWq, lbq, lWkv, lbkv, lng + l * DD, lnb + l * DD);
    k_attn<<<dim3(NSEG, HH, BB), 64, 0, stream>>>(qkv, attn, lens);
    k_oproj<<<ROWS / 16, 256, 0, stream>>>(
        attn, lWo, lbo, x, res, ffln, ffg + l * DD, ffb + l * DD);
    k_ffn1<<<dim3(ROWS / 64, FFND / 64), 256, 0, stream>>>(ffln, lW1, lb1, h);
    k_ffn2<<<dim3(ROWS / 32, NSPLIT), 256, 0, stream>>>(h, lW2, part);
    k_comb<<<ROWS, 128, 0, stream>>>(part, lb2, res, x, og + l * DD, ob + l * DD);
  }

  k_proj<<<dim3(BB * UU / 64, OUTD / 64), 256, 0, stream>>>(x, Wp, bp, lens, out);
}

// Round 2
// 810.712 us; speedup vs baseline: 1.6804x; 1.6804x over previous
//
#include <hip/hip_runtime.h>
#include <math.h>

#define BB 4
#define UU 512
#define DD 80
#define HH 8
#define FFND 2048
#define LL 12
#define SEGC 32
#define LCC 50
#define RCC 8
#define NSEG 16
#define RCL 128
#define KK 640
#define ROWS (BB*KK)        // 2560
#define OUTD 768
#define NSPLIT 8
#define EPSF 1e-5f
#define SCALEF 0.31622776601683794f  // (D/H)^-0.5 = 10^-0.5

typedef __attribute__((ext_vector_type(8))) short bf16x8;
typedef __attribute__((ext_vector_type(4))) float f32x4;

__device__ inline unsigned short f2bf(float f) {
  unsigned int u = __float_as_uint(f);
  u += 0x7fffu + ((u >> 16) & 1u);
  return (unsigned short)(u >> 16);
}

// ---------------- gather: x0 = concat(rc, utt) ----------------
__global__ __launch_bounds__(256) void k_gather(const float* __restrict__ mel,
                                                float* __restrict__ x) {
  int idx = blockIdx.x * 256 + threadIdx.x;
  if (idx >= ROWS * DD) return;
  int d = idx % DD;
  int row = idx / DD;
  int b = row / KK;
  int j = row % KK;
  int pos;
  if (j < RCL) {
    int i = j >> 3, r = j & 7;
    pos = (i < NSEG - 1) ? (i + 1) * SEGC + r : UU + r;
  } else {
    pos = j - RCL;
  }
  x[idx] = mel[(b * (UU + RCC) + pos) * DD + d];
}

// ---------------- convert W1/W2 (all layers) fp32 -> bf16 ----------------
__global__ __launch_bounds__(256) void k_cvt(const float* __restrict__ W1,
                                             const float* __restrict__ W2,
                                             unsigned short* __restrict__ o1,
                                             unsigned short* __restrict__ o2) {
  const int NV = (LL * FFND * DD) / 4;  // float4 count per tensor
  int t = blockIdx.x * 256 + threadIdx.x;
  const float* src;
  unsigned short* dst;
  int i;
  if (t < NV) { src = W1; dst = o1; i = t; }
  else        { src = W2; dst = o2; i = t - NV; }
  float4 v = reinterpret_cast<const float4*>(src)[i];
  ushort4 r;
  r.x = f2bf(v.x); r.y = f2bf(v.y); r.z = f2bf(v.z); r.w = f2bf(v.w);
  reinterpret_cast<ushort4*>(dst)[i] = r;
}

// ---------------- A: LN_in fused + QKV GEMM (fp32) ----------------
__global__ __launch_bounds__(256) void k_qkv(
    const float* __restrict__ x, float* __restrict__ qkv,
    const float* __restrict__ Wq, const float* __restrict__ bq,
    const float* __restrict__ Wkv, const float* __restrict__ bkv,
    const float* __restrict__ lg, const float* __restrict__ lb) {
  __shared__ float s_x[32 * 84];
  __shared__ float s_w[80 * 84];
  __shared__ float s_mu[32], s_ri[32];
  int tid = threadIdx.x;
  int r0 = blockIdx.x * 32;
  int ct = blockIdx.y;
  for (int k = 0; k < 3; ++k) {
    int idx = tid + k * 256;
    if (idx < 640) {
      int row = idx / 20, c4 = idx % 20;
      *reinterpret_cast<float4*>(&s_x[row * 84 + c4 * 4]) =
          *reinterpret_cast<const float4*>(&x[(r0 + row) * DD + c4 * 4]);
    }
  }
  const float* Wbase = (ct == 0) ? Wq : (ct == 1 ? Wkv : (Wkv + 80 * DD));
  for (int k = 0; k < 7; ++k) {
    int idx = tid + k * 256;
    if (idx < 1600) {
      int c = idx / 20, d4 = idx % 20;
      *reinterpret_cast<float4*>(&s_w[c * 84 + d4 * 4]) =
          *reinterpret_cast<const float4*>(&Wbase[c * DD + d4 * 4]);
    }
  }
  __syncthreads();
  {
    int rr = tid >> 3, t8 = tid & 7;
    float sm = 0.f, sq = 0.f;
    for (int d = t8 * 10; d < t8 * 10 + 10; ++d) {
      float v = s_x[rr * 84 + d];
      sm += v; sq += v * v;
    }
    for (int m = 4; m >= 1; m >>= 1) {
      sm += __shfl_xor(sm, m, 8);
      sq += __shfl_xor(sq, m, 8);
    }
    if (t8 == 0) {
      float mu = sm * (1.f / DD);
      float var = sq * (1.f / DD) - mu * mu;
      s_mu[rr] = mu;
      s_ri[rr] = rsqrtf(var + EPSF);
    }
  }
  __syncthreads();
  for (int k = 0; k < 10; ++k) {
    int e = tid + k * 256;
    int row = e / 80, d = e % 80;
    s_x[row * 84 + d] = (s_x[row * 84 + d] - s_mu[row]) * s_ri[row] * lg[d] + lb[d];
  }
  __syncthreads();
  int ty = tid >> 4, tx = tid & 15;
  float acc[2][5] = {};
  for (int d4 = 0; d4 < 20; ++d4) {
    float4 a0 = *reinterpret_cast<const float4*>(&s_x[(2 * ty) * 84 + d4 * 4]);
    float4 a1 = *reinterpret_cast<const float4*>(&s_x[(2 * ty + 1) * 84 + d4 * 4]);
#pragma unroll
    for (int j = 0; j < 5; ++j) {
      float4 w = *reinterpret_cast<const float4*>(&s_w[(tx + 16 * j) * 84 + d4 * 4]);
      acc[0][j] += a0.x * w.x + a0.y * w.y + a0.z * w.z + a0.w * w.w;
      acc[1][j] += a1.x * w.x + a1.y * w.y + a1.z * w.z + a1.w * w.w;
    }
  }
  const float* bias = (ct == 0) ? bq : (bkv + (ct == 2 ? 80 : 0));
  for (int i2 = 0; i2 < 2; ++i2)
    for (int j = 0; j < 5; ++j) {
      int c = tx + 16 * j;
      int grow = r0 + 2 * ty + i2;
      qkv[grow * 240 + ct * 80 + c] = acc[i2][j] + bias[c];
    }
}

// ---------------- B: masked segmented attention ----------------
__global__ __launch_bounds__(64) void k_attn(const float* __restrict__ qkv,
                                             float* __restrict__ attn,
                                             const int* __restrict__ lengths) {
  int i = blockIdx.x, h = blockIdx.y, b = blockIdx.z;
  int tid = threadIdx.x;
  int s = i * SEGC - LCC; if (s < 0) s = 0;
  int e = (i + 1) * SEGC;
  int nk = RCC + (e - s);  // <= 90
  __shared__ float s_k[90 * 10], s_v[90 * 10], s_q[40 * 10];
  __shared__ float s_p[40 * 90], s_kb[90], s_den[40];
  int len = lengths[b];
  for (int j = tid; j < nk; j += 64) {
    int kr = (j < RCC) ? i * RCC + j : RCL + s + (j - RCC);
    const float* kp = &qkv[(b * KK + kr) * 240 + 80 + h * 10];
    const float* vp = &qkv[(b * KK + kr) * 240 + 160 + h * 10];
    for (int d = 0; d < 10; ++d) { s_k[j * 10 + d] = kp[d]; s_v[j * 10 + d] = vp[d]; }
    s_kb[j] = (kr >= len + RCL) ? -1e8f : 0.f;
  }
  if (tid < 40) {
    int j = tid;
    int qr = (j < RCC) ? i * RCC + j : RCL + i * SEGC + (j - RCC);
    const float* qp = &qkv[(b * KK + qr) * 240 + h * 10];
    for (int d = 0; d < 10; ++d) s_q[j * 10 + d] = qp[d];
  }
  __syncthreads();
  for (int p = tid; p < 3600; p += 64) {
    int q = p / 90, jk = p % 90;
    float sc = -1e30f;
    if (jk < nk) {
      float dot = 0.f;
#pragma unroll
      for (int d = 0; d < 10; ++d) dot += s_q[q * 10 + d] * s_k[jk * 10 + d];
      sc = dot * SCALEF + s_kb[jk];
    }
    s_p[p] = sc;
  }
  __syncthreads();
  if (tid < 40) {
    float m = -1e30f;
    for (int kx = 0; kx < 90; ++kx) m = fmaxf(m, s_p[tid * 90 + kx]);
    float sum = 0.f;
    for (int kx = 0; kx < 90; ++kx) {
      float ev = __expf(s_p[tid * 90 + kx] - m);
      s_p[tid * 90 + kx] = ev;
      sum += ev;
    }
    s_den[tid] = sum;
  }
  __syncthreads();
  for (int po = tid; po < 400; po += 64) {
    int q = po / 10, d = po % 10;
    float o = 0.f;
    for (int kx = 0; kx < 90; ++kx) o += s_p[q * 90 + kx] * s_v[kx * 10 + d];
    int qr = (q < RCC) ? i * RCC + q : RCL + i * SEGC + (q - RCC);
    attn[(b * KK + qr) * DD + h * 10 + d] = o / s_den[q];
  }
}

// ---------------- C: out-proj + bias + residual + LN_ff (writes bf16 ffln) ----
__global__ __launch_bounds__(256) void k_oproj(
    const float* __restrict__ attn, const float* __restrict__ Wo,
    const float* __restrict__ bo, const float* __restrict__ x,
    float* __restrict__ res, unsigned short* __restrict__ ffln_bf,
    const float* __restrict__ fg, const float* __restrict__ fb) {
  __shared__ float s_at[16 * 84], s_x2[16 * 84], s_wo[80 * 84];
  int tid = threadIdx.x;
  int r0 = blockIdx.x * 16;
  for (int k = 0; k < 2; ++k) {
    int idx = tid + k * 256;
    if (idx < 320) {
      int row = idx / 20, c4 = idx % 20;
      *reinterpret_cast<float4*>(&s_at[row * 84 + c4 * 4]) =
          *reinterpret_cast<const float4*>(&attn[(r0 + row) * DD + c4 * 4]);
      *reinterpret_cast<float4*>(&s_x2[row * 84 + c4 * 4]) =
          *reinterpret_cast<const float4*>(&x[(r0 + row) * DD + c4 * 4]);
    }
  }
  for (int k = 0; k < 7; ++k) {
    int idx = tid + k * 256;
    if (idx < 1600) {
      int c = idx / 20, d4 = idx % 20;
      *reinterpret_cast<float4*>(&s_wo[c * 84 + d4 * 4]) =
          *reinterpret_cast<const float4*>(&Wo[c * DD + d4 * 4]);
    }
  }
  __syncthreads();
  int r = tid >> 4, tx = tid & 15;
  float acc[5] = {};
  for (int d4 = 0; d4 < 20; ++d4) {
    float4 a = *reinterpret_cast<const float4*>(&s_at[r * 84 + d4 * 4]);
#pragma unroll
    for (int j = 0; j < 5; ++j) {
      float4 w = *reinterpret_cast<const float4*>(&s_wo[(tx + 16 * j) * 84 + d4 * 4]);
      acc[j] += a.x * w.x + a.y * w.y + a.z * w.z + a.w * w.w;
    }
  }
  float val[5];
  float sm = 0.f, sq = 0.f;
#pragma unroll
  for (int j = 0; j < 5; ++j) {
    int c = tx + 16 * j;
    float v = acc[j] + bo[c] + s_x2[r * 84 + c];
    val[j] = v;
    res[(r0 + r) * DD + c] = v;
    sm += v; sq += v * v;
  }
  for (int m = 8; m >= 1; m >>= 1) {
    sm += __shfl_xor(sm, m, 16);
    sq += __shfl_xor(sq, m, 16);
  }
  float mu = sm * (1.f / DD);
  float ri = rsqrtf(sq * (1.f / DD) - mu * mu + EPSF);
#pragma unroll
  for (int j = 0; j < 5; ++j) {
    int c = tx + 16 * j;
    ffln_bf[(r0 + r) * DD + c] = f2bf((val[j] - mu) * ri * fg[c] + fb[c]);
  }
}

// ---------------- D: FFN1 MFMA: h = relu(ffln @ W1^T + b1), bf16 out --------
// grid (2560/128, 2048/128), block 256. K=80 zero-padded to 96.
__global__ __launch_bounds__(256) void k_ffn1m(
    const unsigned short* __restrict__ A, const unsigned short* __restrict__ W,
    const float* __restrict__ b1, unsigned short* __restrict__ h) {
  __shared__ unsigned short s_a[128 * 104];
  __shared__ unsigned short s_b[128 * 104];
  int tid = threadIdx.x;
  int r0 = blockIdx.x * 128, c0 = blockIdx.y * 128;
  for (int k = 0; k < 5; ++k) {
    int idx = tid + k * 256;  // 1280 = 128 rows x 10 chunks of 8 bf16
    int row = idx / 10, ch = idx % 10;
    *reinterpret_cast<uint4*>(&s_a[row * 104 + ch * 8]) =
        *reinterpret_cast<const uint4*>(&A[(r0 + row) * DD + ch * 8]);
    *reinterpret_cast<uint4*>(&s_b[row * 104 + ch * 8]) =
        *reinterpret_cast<const uint4*>(&W[(c0 + row) * DD + ch * 8]);
  }
  {  // zero K-pad 80..95 (one 16B store per thread per buffer)
    int row = tid >> 1, half = tid & 1;
    uint4 z = make_uint4(0, 0, 0, 0);
    *reinterpret_cast<uint4*>(&s_a[row * 104 + 80 + half * 8]) = z;
    *reinterpret_cast<uint4*>(&s_b[row * 104 + 80 + half * 8]) = z;
  }
  __syncthreads();
  int w = tid >> 6, lane = tid & 63;
  int m = lane & 15, q = lane >> 4;
  f32x4 acc[2][8] = {};
#pragma unroll
  for (int kk = 0; kk < 3; ++kk) {
    bf16x8 a0 = *reinterpret_cast<const bf16x8*>(&s_a[(w * 32 + m) * 104 + kk * 32 + q * 8]);
    bf16x8 a1 = *reinterpret_cast<const bf16x8*>(&s_a[(w * 32 + 16 + m) * 104 + kk * 32 + q * 8]);
#pragma unroll
    for (int ct = 0; ct < 8; ++ct) {
      bf16x8 b = *reinterpret_cast<const bf16x8*>(&s_b[(ct * 16 + m) * 104 + kk * 32 + q * 8]);
      acc[0][ct] = __builtin_amdgcn_mfma_f32_16x16x32_bf16(a0, b, acc[0][ct], 0, 0, 0);
      acc[1][ct] = __builtin_amdgcn_mfma_f32_16x16x32_bf16(a1, b, acc[1][ct], 0, 0, 0);
    }
  }
#pragma unroll
  for (int rt = 0; rt < 2; ++rt)
#pragma unroll
    for (int ct = 0; ct < 8; ++ct) {
      int col = c0 + ct * 16 + m;
      float bias = b1[col];
#pragma unroll
      for (int r = 0; r < 4; ++r) {
        int grow = r0 + w * 32 + rt * 16 + q * 4 + r;
        h[grow * FFND + col] = f2bf(fmaxf(acc[rt][ct][r] + bias, 0.f));
      }
    }
}

// ---------------- E: FFN2 MFMA split-K: part[s] = h @ W2^T -------------------
// grid (2560/64, NSPLIT), block 256. Each split covers K=256 (2 sub-chunks of 128).
__global__ __launch_bounds__(256) void k_ffn2m(
    const unsigned short* __restrict__ h, const unsigned short* __restrict__ W2,
    float* __restrict__ part) {
  __shared__ unsigned short s_h[64 * 136];
  __shared__ unsigned short s_w[80 * 136];
  int tid = threadIdx.x;
  int r0 = blockIdx.x * 64;
  int s = blockIdx.y;
  int w = tid >> 6, lane = tid & 63;
  int m = lane & 15, q = lane >> 4;
  f32x4 acc[5] = {};
  for (int sub = 0; sub < 2; ++sub) {
    int kbase = s * 256 + sub * 128;
    __syncthreads();
    for (int k = 0; k < 4; ++k) {
      int idx = tid + k * 256;  // 1024 = 64 rows x 16 chunks
      int row = idx >> 4, ch = idx & 15;
      *reinterpret_cast<uint4*>(&s_h[row * 136 + ch * 8]) =
          *reinterpret_cast<const uint4*>(&h[(r0 + row) * FFND + kbase + ch * 8]);
    }
    for (int k = 0; k < 5; ++k) {
      int idx = tid + k * 256;  // 1280 = 80 rows x 16 chunks
      int row = idx >> 4, ch = idx & 15;
      *reinterpret_cast<uint4*>(&s_w[row * 136 + ch * 8]) =
          *reinterpret_cast<const uint4*>(&W2[row * FFND + kbase + ch * 8]);
    }
    __syncthreads();
#pragma unroll
    for (int kk = 0; kk < 4; ++kk) {
      bf16x8 a = *reinterpret_cast<const bf16x8*>(&s_h[(w * 16 + m) * 136 + kk * 32 + q * 8]);
#pragma unroll
      for (int ct = 0; ct < 5; ++ct) {
        bf16x8 b = *reinterpret_cast<const bf16x8*>(&s_w[(ct * 16 + m) * 136 + kk * 32 + q * 8]);
        acc[ct] = __builtin_amdgcn_mfma_f32_16x16x32_bf16(a, b, acc[ct], 0, 0, 0);
      }
    }
  }
#pragma unroll
  for (int ct = 0; ct < 5; ++ct)
#pragma unroll
    for (int r = 0; r < 4; ++r) {
      int grow = r0 + w * 16 + q * 4 + r;
      part[s * (ROWS * DD) + grow * DD + ct * 16 + m] = acc[ct][r];
    }
}

// ---------------- F: combine splits + b2 + residual + LN_out -> x ------------
__global__ __launch_bounds__(128) void k_comb(
    const float* __restrict__ part, const float* __restrict__ b2,
    const float* __restrict__ res, float* __restrict__ x,
    const float* __restrict__ og, const float* __restrict__ ob) {
  int row = blockIdx.x;
  int t = threadIdx.x;
  __shared__ float rsum[128], rsq[128];
  float v = 0.f;
  if (t < DD) {
#pragma unroll
    for (int s = 0; s < NSPLIT; ++s) v += part[s * (ROWS * DD) + row * DD + t];
    v += b2[t] + res[row * DD + t];
  }
  rsum[t] = (t < DD) ? v : 0.f;
  rsq[t] = (t < DD) ? v * v : 0.f;
  __syncthreads();
  for (int m2 = 64; m2 >= 1; m2 >>= 1) {
    if (t < m2) { rsum[t] += rsum[t + m2]; rsq[t] += rsq[t + m2]; }
    __syncthreads();
  }
  float mu = rsum[0] * (1.f / DD);
  float ri = rsqrtf(rsq[0] * (1.f / DD) - mu * mu + EPSF);
  if (t < DD) x[row * DD + t] = (v - mu) * ri * og[t] + ob[t];
}

// ---------------- P: final projection + lengths tail ----------------
__global__ __launch_bounds__(256) void k_proj(
    const float* __restrict__ x, const float* __restrict__ Wp,
    const float* __restrict__ bp, const int* __restrict__ lengths,
    float* __restrict__ out) {
  __shared__ float s_a[64 * 84], s_w[64 * 84];
  int tid = threadIdx.x;
  int gr0 = blockIdx.x * 64;
  int c0 = blockIdx.y * 64;
  int b = gr0 / UU;
  int u0 = gr0 % UU;
  for (int k = 0; k < 5; ++k) {
    int idx = tid + k * 256;
    int row = idx / 20, c4 = idx % 20;
    *reinterpret_cast<float4*>(&s_a[row * 84 + c4 * 4]) =
        *reinterpret_cast<const float4*>(&x[(b * KK + RCL + u0 + row) * DD + c4 * 4]);
    *reinterpret_cast<float4*>(&s_w[row * 84 + c4 * 4]) =
        *reinterpret_cast<const float4*>(&Wp[(c0 + row) * DD + c4 * 4]);
  }
  __syncthreads();
  int ty = tid >> 4, tx = tid & 15;
  float acc[4][4] = {};
  for (int d4 = 0; d4 < 20; ++d4) {
    float4 a[4], w[4];
#pragma unroll
    for (int i2 = 0; i2 < 4; ++i2)
      a[i2] = *reinterpret_cast<const float4*>(&s_a[(4 * ty + i2) * 84 + d4 * 4]);
#pragma unroll
    for (int j = 0; j < 4; ++j)
      w[j] = *reinterpret_cast<const float4*>(&s_w[(tx + 16 * j) * 84 + d4 * 4]);
#pragma unroll
    for (int i2 = 0; i2 < 4; ++i2)
#pragma unroll
      for (int j = 0; j < 4; ++j)
        acc[i2][j] += a[i2].x * w[j].x + a[i2].y * w[j].y +
                      a[i2].z * w[j].z + a[i2].w * w[j].w;
  }
  for (int i2 = 0; i2 < 4; ++i2)
    for (int j = 0; j < 4; ++j) {
      int c = c0 + tx + 16 * j;
      out[(gr0 + 4 * ty + i2) * OUTD + c] = acc[i2][j] + bp[c];
    }
  if (blockIdx.x == 0 && blockIdx.y == 0 && tid < BB)
    out[BB * UU * OUTD + tid] = (float)lengths[tid];
}

extern "C" void kernel_launch(void* const* d_in, const int* in_sizes, int n_in,
                              void* d_out, int out_size, void* d_ws, size_t ws_size,
                              hipStream_t stream) {
  const float* mel   = (const float*)d_in[0];
  const float* lng   = (const float*)d_in[1];
  const float* lnb   = (const float*)d_in[2];
  const float* Wq    = (const float*)d_in[3];
  const float* bq    = (const float*)d_in[4];
  const float* Wkv   = (const float*)d_in[5];
  const float* bkv   = (const float*)d_in[6];
  const float* Wo    = (const float*)d_in[7];
  const float* bo    = (const float*)d_in[8];
  const float* ffg   = (const float*)d_in[9];
  const float* ffb   = (const float*)d_in[10];
  const float* W1    = (const float*)d_in[11];
  const float* b1    = (const float*)d_in[12];
  const float* W2    = (const float*)d_in[13];
  const float* b2    = (const float*)d_in[14];
  const float* og    = (const float*)d_in[15];
  const float* ob    = (const float*)d_in[16];
  const float* Wp    = (const float*)d_in[17];
  const float* bp    = (const float*)d_in[18];
  const int*   lens  = (const int*)d_in[19];
  float* out = (float*)d_out;

  // workspace layout (floats); part aliases qkv (qkv dead after k_attn,
  // part written by k_ffn2m afterwards, dead before next layer's k_qkv)
  float* ws   = (float*)d_ws;
  float* x    = ws;                          // 204800
  float* qkv  = x + ROWS * DD;               // aliased region: 8*204800
  float* part = qkv;
  float* attn = qkv + NSPLIT * ROWS * DD;    // 204800
  float* res  = attn + ROWS * DD;            // 204800
  unsigned short* ffln_bf = (unsigned short*)(res + ROWS * DD);          // ROWS*80 bf16
  unsigned short* h_bf    = ffln_bf + ROWS * DD;                         // ROWS*2048 bf16
  unsigned short* w1bf    = h_bf + ROWS * FFND;                          // 12*2048*80 bf16
  unsigned short* w2bf    = w1bf + LL * FFND * DD;                       // 12*2048*80 bf16

  k_gather<<<(ROWS * DD + 255) / 256, 256, 0, stream>>>(mel, x);
  k_cvt<<<(2 * (LL * FFND * DD) / 4 + 255) / 256, 256, 0, stream>>>(W1, W2, w1bf, w2bf);

  for (int l = 0; l < LL; ++l) {
    const float* lWq  = Wq  + l * DD * DD;
    const float* lbq  = bq  + l * DD;
    const float* lWkv = Wkv + l * 2 * DD * DD;
    const float* lbkv = bkv + l * 2 * DD;
    const float* lWo  = Wo  + l * DD * DD;
    const float* lbo  = bo  + l * DD;
    const unsigned short* lW1 = w1bf + l * FFND * DD;
    const float* lb1  = b1  + l * FFND;
    const unsigned short* lW2 = w2bf + l * FFND * DD;
    const float* lb2  = b2  + l * DD;

    k_qkv<<<dim3(ROWS / 32, 3), 256, 0, stream>>>(
        x, qkv, lWq, lbq, lWkv, lbkv, lng + l * DD, lnb + l * DD);
    k_attn<<<dim3(NSEG, HH, BB), 64, 0, stream>>>(qkv, attn, lens);
    k_oproj<<<ROWS / 16, 256, 0, stream>>>(
        attn, lWo, lbo, x, res, ffln_bf, ffg + l * DD, ffb + l * DD);
    k_ffn1m<<<dim3(ROWS / 128, FFND / 128), 256, 0, stream>>>(ffln_bf, lW1, lb1, h_bf);
    k_ffn2m<<<dim3(ROWS / 64, NSPLIT), 256, 0, stream>>>(h_bf, lW2, part);
    k_comb<<<ROWS, 128, 0, stream>>>(part, lb2, res, x, og + l * DD, ob + l * DD);
  }

  k_proj<<<dim3(BB * UU / 64, OUTD / 64), 256, 0, stream>>>(x, Wp, bp, lens, out);
}